// Round 7
// baseline (94.992 us; speedup 1.0000x reference)
//
#include <hip/hip_runtime.h>
#include <math.h>

// Exact fusion of: resize(256->1024) -> warp_perspective(affine) -> resize(1024->256).
// R6 (this session): 4 outputs per thread (vertical) with chained-window row
// reuse. Iteration decomposition: total ~= fill(43us, harness) + gap(~17us,
// harness) + kernel(~29us). Tile-shape experiments (8x8 vs 64x1) were
// neutral, so attack WORK VOLUME: vertically-adjacent outputs' 4-row windows
// overlap 3/4 rows. Each thread computes rows i0..i0+3 of one column; when
// windows chain (rb steps exactly +1, same col base - exact whenever scale &
// rotation are off, m11==1.0, ~64% of images) the union is 7 rows -> 21
// dwordx4 loads replace 48, batched up-front (21KB in flight per wave).
// Chain addresses provably equal R0's (min(rb0+k+d,255)*256+base == e[k+d]);
// weights recomputed via the same deterministic FP chain; non-chain waves
// (__all-uniform) take the exact per-output R0 path -> absmax preserved.
// History: R1 LDS staging -10us; R2 XCD swizzle 0; R3 row sweep -17us;
// R4 MLP hoist/no-barrier 0 (kept); R5 64x1 tiling 0 (kept: contiguous stores).

typedef float floatx4 __attribute__((ext_vector_type(4)));

__device__ __forceinline__ floatx4 load4(const float* p) {
    floatx4 v;
    __builtin_memcpy(&v, p, sizeof(v));  // 4B-aligned 16B load -> dwordx4
    return v;
}

struct Up { int i0; float w; };

__device__ __forceinline__ Up upc(int v) {
    float u = fmaf(0.25f, (float)v, -0.375f);
    u = fminf(fmaxf(u, 0.0f), 255.0f);
    float f = floorf(u);
    Up r; r.i0 = (int)f; r.w = u - f;
    return r;
}

struct Trip { float w0, w1, w2; int base; };

__device__ __forceinline__ Trip merged3(float s) {
    float f = floorf(s);
    float fr = s - f;
    int v0 = (int)f;
    int v1 = min(v0 + 1, 1023);
    Up c0 = upc(v0), c1 = upc(v1);
    float A0 = 1.0f - fr, A1 = fr;
    float b0 = A1 * (1.0f - c1.w), b1 = A1 * c1.w;
    bool d = (c1.i0 != c0.i0);
    Trip t;
    t.w0 = A0 * (1.0f - c0.w) + (d ? 0.0f : b0);
    t.w1 = A0 * c0.w + (d ? b0 : b1);
    t.w2 = d ? b1 : 0.0f;
    t.base = c0.i0;
    return t;
}

// Same base chain as merged3(...).base (deterministic, bit-identical).
__device__ __forceinline__ int basefun(float s) {
    float f = floorf(s);
    int v0 = (int)f;
    float u = fmaf(0.25f, (float)v0, -0.375f);
    u = fminf(fmaxf(u, 0.0f), 255.0f);
    return (int)floorf(u);
}

// Exact round-4 pair accumulation (fallback for rare wide-spread threads).
__device__ __forceinline__ void pair_accum(
    Trip cA, Trip cB, Trip rA, Trip rB,
    const float* __restrict__ xb, float* acc)
{
    int cb = min(cA.base, cB.base);
    int rb = min(rA.base, rB.base);
    float CA[4], CB[4], RA[4], RB[4];
    bool sa_ = (cA.base != cb);
    CA[0] = sa_ ? 0.f : cA.w0;  CA[1] = sa_ ? cA.w0 : cA.w1;
    CA[2] = sa_ ? cA.w1 : cA.w2;  CA[3] = sa_ ? cA.w2 : 0.f;
    bool sb_ = (cB.base != cb);
    CB[0] = sb_ ? 0.f : cB.w0;  CB[1] = sb_ ? cB.w0 : cB.w1;
    CB[2] = sb_ ? cB.w1 : cB.w2;  CB[3] = sb_ ? cB.w2 : 0.f;
    bool ra_ = (rA.base != rb);
    RA[0] = ra_ ? 0.f : rA.w0;  RA[1] = ra_ ? rA.w0 : rA.w1;
    RA[2] = ra_ ? rA.w1 : rA.w2;  RA[3] = ra_ ? rA.w2 : 0.f;
    bool rb_ = (rB.base != rb);
    RB[0] = rb_ ? 0.f : rB.w0;  RB[1] = rb_ ? rB.w0 : rB.w1;
    RB[2] = rb_ ? rB.w1 : rB.w2;  RB[3] = rb_ ? rB.w2 : 0.f;

    float W[4][4];
#pragma unroll
    for (int r = 0; r < 4; ++r)
#pragma unroll
        for (int c = 0; c < 4; ++c)
            W[r][c] = fmaf(RB[r], CB[c], RA[r] * CA[c]);

    int base = cb;
    if (cb > 252) {
        int shift = cb - 252;
        base = 252;
        for (int s = 0; s < shift; ++s) {
#pragma unroll
            for (int r = 0; r < 4; ++r) {
                W[r][3] = W[r][2]; W[r][2] = W[r][1];
                W[r][1] = W[r][0]; W[r][0] = 0.f;
            }
        }
    }
    int e0 = rb * 256 + base;
    int e1 = min(rb + 1, 255) * 256 + base;
    int e2 = min(rb + 2, 255) * 256 + base;
    int e3 = min(rb + 3, 255) * 256 + base;
#pragma unroll
    for (int ch = 0; ch < 3; ++ch) {
        const float* pc = xb + ch * 65536;
        floatx4 L0 = load4(pc + e0);
        floatx4 L1 = load4(pc + e1);
        floatx4 L2 = load4(pc + e2);
        floatx4 L3 = load4(pc + e3);
        float s0 = fmaf(W[0][3], L0.w, fmaf(W[0][2], L0.z, fmaf(W[0][1], L0.y, W[0][0] * L0.x)));
        float s1 = fmaf(W[1][3], L1.w, fmaf(W[1][2], L1.z, fmaf(W[1][1], L1.y, W[1][0] * L1.x)));
        float s2 = fmaf(W[2][3], L2.w, fmaf(W[2][2], L2.z, fmaf(W[2][1], L2.y, W[2][0] * L2.x)));
        float s3 = fmaf(W[3][3], L3.w, fmaf(W[3][2], L3.z, fmaf(W[3][1], L3.y, W[3][0] * L3.x)));
        acc[ch] += (s0 + s1) + (s2 + s3);
    }
}

__global__ __launch_bounds__(256) void fused_warp(
    const float* __restrict__ x,
    const float* __restrict__ paramP, const float* __restrict__ paramM,
    const float* __restrict__ gumbel_u, const float* __restrict__ eps,
    const int* __restrict__ idx,
    float* __restrict__ out, int N)
{
    int b = blockIdx.z;
    int lane = threadIdx.x;      // 0..63: output column within 64-wide tile
    int ty   = threadIdx.y;      // 0..3 : which 4-row strip

    // ---- per-wave redundant matrix computation (no barrier, no LDS) ----
    float dec = 0.f, sMv = 0.f;
    if (lane < 7) {
        int k = lane;
        int id = idx[b];
        float vP = paramP[k * N + id];
        float pP = 1.0f / (1.0f + expf(-vP));
        float l0 = logf(pP);
        float l1 = logf(1.0f - pP);
        float u0 = gumbel_u[(k * 16 + b) * 2 + 0];
        float u1 = gumbel_u[(k * 16 + b) * 2 + 1];
        float g0 = -logf(-logf(u0));
        float g1 = -logf(-logf(u1));
        dec = (l0 + g0 >= l1 + g1) ? 1.0f : 0.0f;  // argmax tie -> index 0
        float vM = paramM[k * N + id];
        float sig = 1.0f / (1.0f + expf(-vM));
        sMv = sig * eps[k * 16 + b];
    }
    float sP[7], sM[7];
#pragma unroll
    for (int k = 0; k < 7; ++k) {
        sP[k] = __shfl(dec, k, 64);
        sM[k] = __shfl(sMv, k, 64);
    }

    float ang = sP[0] * sM[0] * 30.0f;
    float rad = ang * 0.017453292519943295f;
    float ca = cosf(rad), sa = sinf(rad);
    float sxs = 1.0f + sP[5] * sM[5] * 0.5f;
    float sys = 1.0f + sP[6] * sM[6] * 0.5f;
    float sr00 = ca * sxs, sr01 = sa * sys;
    float sr10 = -sa * sxs, sr11 = ca * sys;
    float t0 = 128.0f - (sr00 + sr01) * 128.0f;
    float t1 = 128.0f - (sr10 + sr11) * 128.0f;
    float tx2 = 256.0f * sP[1] * sM[1] * 0.45f;
    float ty2 = 256.0f * sP[2] * sM[2] * 0.45f;
    float sh01 = sP[3] * sM[3] * 0.3f;
    float sh10 = sP[4] * sM[4] * 0.3f;
    float e0m = t0 + tx2, e1m = t1 + ty2;
    float a  = sr00 + sh01 * sr10;
    float bb = sr01 + sh01 * sr11;
    float txm = e0m + sh01 * e1m;
    float c  = sh10 * sr00 + sr10;
    float d  = sh10 * sr01 + sr11;
    float tym = sh10 * e0m + e1m;
    float det = a * d - bb * c;
    float rdet = 1.0f / det;
    float m00 = d * rdet;
    float m01 = -bb * rdet;
    float m02 = (bb * tym - d * txm) * rdet;
    float m10 = -c * rdet;
    float m11 = a * rdet;
    float m12 = (c * txm - a * tym) * rdet;

    int j  = blockIdx.x * 64 + lane;
    int i0 = (blockIdx.y * 4 + ty) * 4;

    const float* xb = x + b * 3 * 65536;
    float XA = (float)(4 * j + 1);

    // ---- pass A: per-output window bases + fast flags (lightweight) ----
    int rbk[4], cbk[4];
    bool fk[4];
    bool chainl = true;
#pragma unroll
    for (int k = 0; k < 4; ++k) {
        float Y0 = (float)(4 * (i0 + k) + 1);
        float x0 = fmaf(m00, XA, fmaf(m01, Y0, m02));
        float y0 = fmaf(m10, XA, fmaf(m11, Y0, m12));
        float xs0 = fminf(fmaxf(x0, 0.f), 1023.f);
        float xs1 = fminf(fmaxf(x0 + m00, 0.f), 1023.f);
        float xs2 = fminf(fmaxf(x0 + m01, 0.f), 1023.f);
        float xs3 = fminf(fmaxf((x0 + m00) + m01, 0.f), 1023.f);
        float ys0 = fminf(fmaxf(y0, 0.f), 1023.f);
        float ys1 = fminf(fmaxf(y0 + m10, 0.f), 1023.f);
        float ys2 = fminf(fmaxf(y0 + m11, 0.f), 1023.f);
        float ys3 = fminf(fmaxf((y0 + m10) + m11, 0.f), 1023.f);
        int c0 = basefun(xs0), c1 = basefun(xs1), c2 = basefun(xs2), c3 = basefun(xs3);
        int r0 = basefun(ys0), r1 = basefun(ys1), r2 = basefun(ys2), r3 = basefun(ys3);
        int cmn = min(min(c0, c1), min(c2, c3));
        int cmx = max(max(c0, c1), max(c2, c3));
        int rmn = min(min(r0, r1), min(r2, r3));
        int rmx = max(max(r0, r1), max(r2, r3));
        cbk[k] = cmn; rbk[k] = rmn;
        fk[k] = (((cmx - cmn) | (rmx - rmn)) <= 1);
        chainl = chainl && fk[k] && (cbk[k] == cbk[0]) && (rbk[k] == rbk[0] + k);
    }
    bool chain = __all(chainl);   // wave-uniform branch (no dual execution)

    float acc[4][3];
#pragma unroll
    for (int k = 0; k < 4; ++k) {
        acc[k][0] = 0.f; acc[k][1] = 0.f; acc[k][2] = 0.f;
    }

    if (chain) {
        // ---- chained fast path: 7 shared rows, 21 loads for 4 outputs ----
        int rb0 = rbk[0];
        int base = (cbk[0] > 252) ? 252 : cbk[0];
        floatx4 RA[7], RB[7], RD[7];
#pragma unroll
        for (int t = 0; t < 7; ++t) {
            int et = min(rb0 + t, 255) * 256 + base;
            RA[t] = load4(xb + et);
            RB[t] = load4(xb + 65536 + et);
            RD[t] = load4(xb + 131072 + et);
        }
#pragma unroll
        for (int k = 0; k < 4; ++k) {
            // recompute Trips + W exactly as the R0 fast path
            float Y0 = (float)(4 * (i0 + k) + 1);
            float x0 = fmaf(m00, XA, fmaf(m01, Y0, m02));
            float y0 = fmaf(m10, XA, fmaf(m11, Y0, m12));
            float xs[4], ys[4];
            xs[0] = x0;          ys[0] = y0;
            xs[1] = x0 + m00;    ys[1] = y0 + m10;
            xs[2] = x0 + m01;    ys[2] = y0 + m11;
            xs[3] = xs[1] + m01; ys[3] = ys[1] + m11;
            Trip cx[4], ry[4];
#pragma unroll
            for (int s = 0; s < 4; ++s) {
                cx[s] = merged3(fminf(fmaxf(xs[s], 0.f), 1023.f));
                ry[s] = merged3(fminf(fmaxf(ys[s], 0.f), 1023.f));
            }
            int cbmin = min(min(cx[0].base, cx[1].base), min(cx[2].base, cx[3].base));
            int rbmin = min(min(ry[0].base, ry[1].base), min(ry[2].base, ry[3].base));
            (void)rbmin;  // == rb0 + k by chain condition
            float W[4][4];
#pragma unroll
            for (int s = 0; s < 4; ++s) {
                bool sc = (cx[s].base != cbmin);
                float C0 = sc ? 0.f : cx[s].w0;
                float C1 = sc ? cx[s].w0 : cx[s].w1;
                float C2 = sc ? cx[s].w1 : cx[s].w2;
                float C3 = sc ? cx[s].w2 : 0.f;
                bool sr = (ry[s].base != rbk[k]);
                float R0 = sr ? 0.f : ry[s].w0;
                float R1 = sr ? ry[s].w0 : ry[s].w1;
                float R2 = sr ? ry[s].w1 : ry[s].w2;
                float R3 = sr ? ry[s].w2 : 0.f;
                float C[4] = {C0, C1, C2, C3};
                float R[4] = {R0, R1, R2, R3};
                if (s == 0) {
#pragma unroll
                    for (int r = 0; r < 4; ++r)
#pragma unroll
                        for (int cc = 0; cc < 4; ++cc)
                            W[r][cc] = R[r] * C[cc];
                } else {
#pragma unroll
                    for (int r = 0; r < 4; ++r)
#pragma unroll
                        for (int cc = 0; cc < 4; ++cc)
                            W[r][cc] = fmaf(R[r], C[cc], W[r][cc]);
                }
            }
            if (cbmin > 252) {
                int shift = cbmin - 252;
                for (int s = 0; s < shift; ++s) {
#pragma unroll
                    for (int r = 0; r < 4; ++r) {
                        W[r][3] = W[r][2]; W[r][2] = W[r][1];
                        W[r][1] = W[r][0]; W[r][0] = 0.f;
                    }
                }
            }
            {
                float s0 = fmaf(W[0][3], RA[k+0].w, fmaf(W[0][2], RA[k+0].z, fmaf(W[0][1], RA[k+0].y, W[0][0] * RA[k+0].x)));
                float s1 = fmaf(W[1][3], RA[k+1].w, fmaf(W[1][2], RA[k+1].z, fmaf(W[1][1], RA[k+1].y, W[1][0] * RA[k+1].x)));
                float s2 = fmaf(W[2][3], RA[k+2].w, fmaf(W[2][2], RA[k+2].z, fmaf(W[2][1], RA[k+2].y, W[2][0] * RA[k+2].x)));
                float s3 = fmaf(W[3][3], RA[k+3].w, fmaf(W[3][2], RA[k+3].z, fmaf(W[3][1], RA[k+3].y, W[3][0] * RA[k+3].x)));
                acc[k][0] = (s0 + s1) + (s2 + s3);
            }
            {
                float s0 = fmaf(W[0][3], RB[k+0].w, fmaf(W[0][2], RB[k+0].z, fmaf(W[0][1], RB[k+0].y, W[0][0] * RB[k+0].x)));
                float s1 = fmaf(W[1][3], RB[k+1].w, fmaf(W[1][2], RB[k+1].z, fmaf(W[1][1], RB[k+1].y, W[1][0] * RB[k+1].x)));
                float s2 = fmaf(W[2][3], RB[k+2].w, fmaf(W[2][2], RB[k+2].z, fmaf(W[2][1], RB[k+2].y, W[2][0] * RB[k+2].x)));
                float s3 = fmaf(W[3][3], RB[k+3].w, fmaf(W[3][2], RB[k+3].z, fmaf(W[3][1], RB[k+3].y, W[3][0] * RB[k+3].x)));
                acc[k][1] = (s0 + s1) + (s2 + s3);
            }
            {
                float s0 = fmaf(W[0][3], RD[k+0].w, fmaf(W[0][2], RD[k+0].z, fmaf(W[0][1], RD[k+0].y, W[0][0] * RD[k+0].x)));
                float s1 = fmaf(W[1][3], RD[k+1].w, fmaf(W[1][2], RD[k+1].z, fmaf(W[1][1], RD[k+1].y, W[1][0] * RD[k+1].x)));
                float s2 = fmaf(W[2][3], RD[k+2].w, fmaf(W[2][2], RD[k+2].z, fmaf(W[2][1], RD[k+2].y, W[2][0] * RD[k+2].x)));
                float s3 = fmaf(W[3][3], RD[k+3].w, fmaf(W[3][2], RD[k+3].z, fmaf(W[3][1], RD[k+3].y, W[3][0] * RD[k+3].x)));
                acc[k][2] = (s0 + s1) + (s2 + s3);
            }
        }
    } else {
        // ---- per-output path: exact R0 structure, 4x ----
#pragma unroll
        for (int k = 0; k < 4; ++k) {
            float Y0 = (float)(4 * (i0 + k) + 1);
            float x0 = fmaf(m00, XA, fmaf(m01, Y0, m02));
            float y0 = fmaf(m10, XA, fmaf(m11, Y0, m12));
            float xs[4], ys[4];
            xs[0] = x0;          ys[0] = y0;
            xs[1] = x0 + m00;    ys[1] = y0 + m10;
            xs[2] = x0 + m01;    ys[2] = y0 + m11;
            xs[3] = xs[1] + m01; ys[3] = ys[1] + m11;
            Trip cx[4], ry[4];
#pragma unroll
            for (int s = 0; s < 4; ++s) {
                cx[s] = merged3(fminf(fmaxf(xs[s], 0.f), 1023.f));
                ry[s] = merged3(fminf(fmaxf(ys[s], 0.f), 1023.f));
            }
            int cbmin = min(min(cx[0].base, cx[1].base), min(cx[2].base, cx[3].base));
            int cbmax = max(max(cx[0].base, cx[1].base), max(cx[2].base, cx[3].base));
            int rbmin = min(min(ry[0].base, ry[1].base), min(ry[2].base, ry[3].base));
            int rbmax = max(max(ry[0].base, ry[1].base), max(ry[2].base, ry[3].base));

            if (((cbmax - cbmin) | (rbmax - rbmin)) <= 1) {
                float W[4][4];
#pragma unroll
                for (int s = 0; s < 4; ++s) {
                    bool sc = (cx[s].base != cbmin);
                    float C0 = sc ? 0.f : cx[s].w0;
                    float C1 = sc ? cx[s].w0 : cx[s].w1;
                    float C2 = sc ? cx[s].w1 : cx[s].w2;
                    float C3 = sc ? cx[s].w2 : 0.f;
                    bool sr = (ry[s].base != rbmin);
                    float R0 = sr ? 0.f : ry[s].w0;
                    float R1 = sr ? ry[s].w0 : ry[s].w1;
                    float R2 = sr ? ry[s].w1 : ry[s].w2;
                    float R3 = sr ? ry[s].w2 : 0.f;
                    float C[4] = {C0, C1, C2, C3};
                    float R[4] = {R0, R1, R2, R3};
                    if (s == 0) {
#pragma unroll
                        for (int r = 0; r < 4; ++r)
#pragma unroll
                            for (int cc = 0; cc < 4; ++cc)
                                W[r][cc] = R[r] * C[cc];
                    } else {
#pragma unroll
                        for (int r = 0; r < 4; ++r)
#pragma unroll
                            for (int cc = 0; cc < 4; ++cc)
                                W[r][cc] = fmaf(R[r], C[cc], W[r][cc]);
                    }
                }
                int base = cbmin;
                if (cbmin > 252) {
                    int shift = cbmin - 252;
                    base = 252;
                    for (int s = 0; s < shift; ++s) {
#pragma unroll
                        for (int r = 0; r < 4; ++r) {
                            W[r][3] = W[r][2]; W[r][2] = W[r][1];
                            W[r][1] = W[r][0]; W[r][0] = 0.f;
                        }
                    }
                }
                int e0 = rbmin * 256 + base;
                int e1 = min(rbmin + 1, 255) * 256 + base;
                int e2 = min(rbmin + 2, 255) * 256 + base;
                int e3 = min(rbmin + 3, 255) * 256 + base;
                const float* p0 = xb;
                const float* p1 = xb + 65536;
                const float* p2 = xb + 131072;
                floatx4 A0 = load4(p0 + e0);
                floatx4 A1 = load4(p0 + e1);
                floatx4 A2 = load4(p0 + e2);
                floatx4 A3 = load4(p0 + e3);
                floatx4 B0 = load4(p1 + e0);
                floatx4 B1 = load4(p1 + e1);
                floatx4 B2 = load4(p1 + e2);
                floatx4 B3 = load4(p1 + e3);
                floatx4 D0 = load4(p2 + e0);
                floatx4 D1 = load4(p2 + e1);
                floatx4 D2 = load4(p2 + e2);
                floatx4 D3 = load4(p2 + e3);
                {
                    float s0 = fmaf(W[0][3], A0.w, fmaf(W[0][2], A0.z, fmaf(W[0][1], A0.y, W[0][0] * A0.x)));
                    float s1 = fmaf(W[1][3], A1.w, fmaf(W[1][2], A1.z, fmaf(W[1][1], A1.y, W[1][0] * A1.x)));
                    float s2 = fmaf(W[2][3], A2.w, fmaf(W[2][2], A2.z, fmaf(W[2][1], A2.y, W[2][0] * A2.x)));
                    float s3 = fmaf(W[3][3], A3.w, fmaf(W[3][2], A3.z, fmaf(W[3][1], A3.y, W[3][0] * A3.x)));
                    acc[k][0] = (s0 + s1) + (s2 + s3);
                }
                {
                    float s0 = fmaf(W[0][3], B0.w, fmaf(W[0][2], B0.z, fmaf(W[0][1], B0.y, W[0][0] * B0.x)));
                    float s1 = fmaf(W[1][3], B1.w, fmaf(W[1][2], B1.z, fmaf(W[1][1], B1.y, W[1][0] * B1.x)));
                    float s2 = fmaf(W[2][3], B2.w, fmaf(W[2][2], B2.z, fmaf(W[2][1], B2.y, W[2][0] * B2.x)));
                    float s3 = fmaf(W[3][3], B3.w, fmaf(W[3][2], B3.z, fmaf(W[3][1], B3.y, W[3][0] * B3.x)));
                    acc[k][1] = (s0 + s1) + (s2 + s3);
                }
                {
                    float s0 = fmaf(W[0][3], D0.w, fmaf(W[0][2], D0.z, fmaf(W[0][1], D0.y, W[0][0] * D0.x)));
                    float s1 = fmaf(W[1][3], D1.w, fmaf(W[1][2], D1.z, fmaf(W[1][1], D1.y, W[1][0] * D1.x)));
                    float s2 = fmaf(W[2][3], D2.w, fmaf(W[2][2], D2.z, fmaf(W[2][1], D2.y, W[2][0] * D2.x)));
                    float s3 = fmaf(W[3][3], D3.w, fmaf(W[3][2], D3.z, fmaf(W[3][1], D3.y, W[3][0] * D3.x)));
                    acc[k][2] = (s0 + s1) + (s2 + s3);
                }
            } else {
                pair_accum(cx[0], cx[1], ry[0], ry[1], xb, acc[k]);
                pair_accum(cx[2], cx[3], ry[2], ry[3], xb, acc[k]);
            }
        }
    }

#pragma unroll
    for (int k = 0; k < 4; ++k) {
        int obase = ((b * 3) * 256 + (i0 + k)) * 256 + j;
        out[obase]          = 0.25f * acc[k][0];
        out[obase + 65536]  = 0.25f * acc[k][1];
        out[obase + 131072] = 0.25f * acc[k][2];
    }
}

extern "C" void kernel_launch(void* const* d_in, const int* in_sizes, int n_in,
                              void* d_out, int out_size, void* d_ws, size_t ws_size,
                              hipStream_t stream) {
    const float* x      = (const float*)d_in[0];
    const float* paramP = (const float*)d_in[1];
    const float* paramM = (const float*)d_in[2];
    const float* gumbel = (const float*)d_in[3];
    const float* eps    = (const float*)d_in[4];
    const int*   idx    = (const int*)d_in[5];
    float* out = (float*)d_out;
    int N = in_sizes[1] / 7;

    hipLaunchKernelGGL(fused_warp, dim3(4, 16, 16), dim3(64, 4, 1), 0, stream,
                       x, paramP, paramM, gumbel, eps, idx, out, N);
}

// Round 9
// 92.990 us; speedup vs baseline: 1.0215x; 1.0215x over previous
//
#include <hip/hip_runtime.h>
#include <math.h>

// Exact fusion of: resize(256->1024) -> warp_perspective(affine) -> resize(1024->256).
// R7 (this session): streaming L3 prefetch + unchanged R5 gather kernel.
// Evidence: tilings with 22 vs 5 L1-lines/instr perform identically; LDS
// staging, MLP hoist, load-dedup all neutral-or-worse -> the ~29us kernel is
// bound by HBM random-64B-line fetch of the L3-cold input (the harness's
// 256MB fill == L3 size scrubs Infinity Cache every iteration; R3 profile:
// 733 GB/s effective). Fix: a 2-3us grid-stride streaming prefetch pulls the
// 12.6MB input into L3 sequentially; the gather then hits L3. Main kernel
// math untouched -> absmax preserved.
// R8: resubmitted unchanged - R7's bench run died to an infrastructure
// failure (container failed twice); the prefetch hypothesis is untested.
// History: R1 LDS staging -10us; R2 XCD swizzle 0; R3 row sweep -17us;
// R4 MLP hoist/no-barrier 0 (kept); R5 64x1 tiling 0 (kept); R6 4-out chain -6us.

typedef float floatx4 __attribute__((ext_vector_type(4)));

__device__ __forceinline__ floatx4 load4(const float* p) {
    floatx4 v;
    __builtin_memcpy(&v, p, sizeof(v));  // 4B-aligned 16B load -> dwordx4
    return v;
}

// ---- streaming prefetch: pull x (12.6MB) into L3 at sequential-line BW ----
__global__ __launch_bounds__(256) void prefetch_x(
    const float* __restrict__ x, int n4)
{
    int t = blockIdx.x * 256 + threadIdx.x;
    float s0 = 0.f, s1 = 0.f, s2 = 0.f, s3 = 0.f;
    for (int i = t; i < n4; i += gridDim.x * 256) {
        floatx4 v = load4(x + 4 * i);
        s0 += v.x; s1 += v.y; s2 += v.z; s3 += v.w;
    }
    // keep the loads alive without any memory side effect (rule #17)
    asm volatile("" :: "v"(s0), "v"(s1), "v"(s2), "v"(s3));
}

struct Up { int i0; float w; };

__device__ __forceinline__ Up upc(int v) {
    float u = fmaf(0.25f, (float)v, -0.375f);
    u = fminf(fmaxf(u, 0.0f), 255.0f);
    float f = floorf(u);
    Up r; r.i0 = (int)f; r.w = u - f;
    return r;
}

struct Trip { float w0, w1, w2; int base; };

__device__ __forceinline__ Trip merged3(float s) {
    float f = floorf(s);
    float fr = s - f;
    int v0 = (int)f;
    int v1 = min(v0 + 1, 1023);
    Up c0 = upc(v0), c1 = upc(v1);
    float A0 = 1.0f - fr, A1 = fr;
    float b0 = A1 * (1.0f - c1.w), b1 = A1 * c1.w;
    bool d = (c1.i0 != c0.i0);
    Trip t;
    t.w0 = A0 * (1.0f - c0.w) + (d ? 0.0f : b0);
    t.w1 = A0 * c0.w + (d ? b0 : b1);
    t.w2 = d ? b1 : 0.0f;
    t.base = c0.i0;
    return t;
}

// Exact round-4 pair accumulation (fallback for rare wide-spread threads).
__device__ __forceinline__ void pair_accum(
    Trip cA, Trip cB, Trip rA, Trip rB,
    const float* __restrict__ xb, float* acc)
{
    int cb = min(cA.base, cB.base);
    int rb = min(rA.base, rB.base);
    float CA[4], CB[4], RA[4], RB[4];
    bool sa_ = (cA.base != cb);
    CA[0] = sa_ ? 0.f : cA.w0;  CA[1] = sa_ ? cA.w0 : cA.w1;
    CA[2] = sa_ ? cA.w1 : cA.w2;  CA[3] = sa_ ? cA.w2 : 0.f;
    bool sb_ = (cB.base != cb);
    CB[0] = sb_ ? 0.f : cB.w0;  CB[1] = sb_ ? cB.w0 : cB.w1;
    CB[2] = sb_ ? cB.w1 : cB.w2;  CB[3] = sb_ ? cB.w2 : 0.f;
    bool ra_ = (rA.base != rb);
    RA[0] = ra_ ? 0.f : rA.w0;  RA[1] = ra_ ? rA.w0 : rA.w1;
    RA[2] = ra_ ? rA.w1 : rA.w2;  RA[3] = ra_ ? rA.w2 : 0.f;
    bool rb_ = (rB.base != rb);
    RB[0] = rb_ ? 0.f : rB.w0;  RB[1] = rb_ ? rB.w0 : rB.w1;
    RB[2] = rb_ ? rB.w1 : rB.w2;  RB[3] = rb_ ? rB.w2 : 0.f;

    float W[4][4];
#pragma unroll
    for (int r = 0; r < 4; ++r)
#pragma unroll
        for (int c = 0; c < 4; ++c)
            W[r][c] = fmaf(RB[r], CB[c], RA[r] * CA[c]);

    int base = cb;
    if (cb > 252) {
        int shift = cb - 252;
        base = 252;
        for (int s = 0; s < shift; ++s) {
#pragma unroll
            for (int r = 0; r < 4; ++r) {
                W[r][3] = W[r][2]; W[r][2] = W[r][1];
                W[r][1] = W[r][0]; W[r][0] = 0.f;
            }
        }
    }
    int e0 = rb * 256 + base;
    int e1 = min(rb + 1, 255) * 256 + base;
    int e2 = min(rb + 2, 255) * 256 + base;
    int e3 = min(rb + 3, 255) * 256 + base;
#pragma unroll
    for (int ch = 0; ch < 3; ++ch) {
        const float* pc = xb + ch * 65536;
        floatx4 L0 = load4(pc + e0);
        floatx4 L1 = load4(pc + e1);
        floatx4 L2 = load4(pc + e2);
        floatx4 L3 = load4(pc + e3);
        float s0 = fmaf(W[0][3], L0.w, fmaf(W[0][2], L0.z, fmaf(W[0][1], L0.y, W[0][0] * L0.x)));
        float s1 = fmaf(W[1][3], L1.w, fmaf(W[1][2], L1.z, fmaf(W[1][1], L1.y, W[1][0] * L1.x)));
        float s2 = fmaf(W[2][3], L2.w, fmaf(W[2][2], L2.z, fmaf(W[2][1], L2.y, W[2][0] * L2.x)));
        float s3 = fmaf(W[3][3], L3.w, fmaf(W[3][2], L3.z, fmaf(W[3][1], L3.y, W[3][0] * L3.x)));
        acc[ch] += (s0 + s1) + (s2 + s3);
    }
}

__global__ __launch_bounds__(256) void fused_warp(
    const float* __restrict__ x,
    const float* __restrict__ paramP, const float* __restrict__ paramM,
    const float* __restrict__ gumbel_u, const float* __restrict__ eps,
    const int* __restrict__ idx,
    float* __restrict__ out, int N)
{
    int b = blockIdx.z;
    int lane = threadIdx.x;      // 0..63: output column within the 64-wide tile
    int wid  = threadIdx.y;      // 0..3 : output row within the 4-tall tile

    // ---- per-wave redundant matrix computation (no barrier, no LDS) ----
    float dec = 0.f, sMv = 0.f;
    if (lane < 7) {
        int k = lane;
        int id = idx[b];
        float vP = paramP[k * N + id];
        float pP = 1.0f / (1.0f + expf(-vP));
        float l0 = logf(pP);
        float l1 = logf(1.0f - pP);
        float u0 = gumbel_u[(k * 16 + b) * 2 + 0];
        float u1 = gumbel_u[(k * 16 + b) * 2 + 1];
        float g0 = -logf(-logf(u0));
        float g1 = -logf(-logf(u1));
        dec = (l0 + g0 >= l1 + g1) ? 1.0f : 0.0f;  // argmax tie -> index 0
        float vM = paramM[k * N + id];
        float sig = 1.0f / (1.0f + expf(-vM));
        sMv = sig * eps[k * 16 + b];
    }
    float sP[7], sM[7];
#pragma unroll
    for (int k = 0; k < 7; ++k) {
        sP[k] = __shfl(dec, k, 64);
        sM[k] = __shfl(sMv, k, 64);
    }

    float ang = sP[0] * sM[0] * 30.0f;
    float rad = ang * 0.017453292519943295f;
    float ca = cosf(rad), sa = sinf(rad);
    float sx = 1.0f + sP[5] * sM[5] * 0.5f;
    float sy = 1.0f + sP[6] * sM[6] * 0.5f;
    float sr00 = ca * sx, sr01 = sa * sy;
    float sr10 = -sa * sx, sr11 = ca * sy;
    float t0 = 128.0f - (sr00 + sr01) * 128.0f;
    float t1 = 128.0f - (sr10 + sr11) * 128.0f;
    float tx2 = 256.0f * sP[1] * sM[1] * 0.45f;
    float ty2 = 256.0f * sP[2] * sM[2] * 0.45f;
    float sh01 = sP[3] * sM[3] * 0.3f;
    float sh10 = sP[4] * sM[4] * 0.3f;
    float e0m = t0 + tx2, e1m = t1 + ty2;
    float a  = sr00 + sh01 * sr10;
    float bb = sr01 + sh01 * sr11;
    float txm = e0m + sh01 * e1m;
    float c  = sh10 * sr00 + sr10;
    float d  = sh10 * sr01 + sr11;
    float tym = sh10 * e0m + e1m;
    float det = a * d - bb * c;
    float rdet = 1.0f / det;
    float m00 = d * rdet;
    float m01 = -bb * rdet;
    float m02 = (bb * tym - d * txm) * rdet;
    float m10 = -c * rdet;
    float m11 = a * rdet;
    float m12 = (c * txm - a * tym) * rdet;

    // ---- 64x1 wave tiling: all 64 lanes on ONE output row; contiguous stores.
    int j = blockIdx.x * 64 + lane;
    int i = blockIdx.y * 4 + wid;

    const float* xb = x + b * 3 * 65536;

    float XA = (float)(4 * j + 1);
    float Y0 = (float)(4 * i + 1);
    float x0 = fmaf(m00, XA, fmaf(m01, Y0, m02));
    float y0 = fmaf(m10, XA, fmaf(m11, Y0, m12));
    float xs[4], ys[4];
    xs[0] = x0;        ys[0] = y0;
    xs[1] = x0 + m00;  ys[1] = y0 + m10;
    xs[2] = x0 + m01;  ys[2] = y0 + m11;
    xs[3] = xs[1] + m01; ys[3] = ys[1] + m11;

    Trip cx[4], ry[4];
#pragma unroll
    for (int s = 0; s < 4; ++s) {
        cx[s] = merged3(fminf(fmaxf(xs[s], 0.f), 1023.f));
        ry[s] = merged3(fminf(fmaxf(ys[s], 0.f), 1023.f));
    }

    int cbmin = min(min(cx[0].base, cx[1].base), min(cx[2].base, cx[3].base));
    int cbmax = max(max(cx[0].base, cx[1].base), max(cx[2].base, cx[3].base));
    int rbmin = min(min(ry[0].base, ry[1].base), min(ry[2].base, ry[3].base));
    int rbmax = max(max(ry[0].base, ry[1].base), max(ry[2].base, ry[3].base));

    float acc[3] = {0.f, 0.f, 0.f};

    if (((cbmax - cbmin) | (rbmax - rbmin)) <= 1) {
        // ---- fast path: single 4x4 union window, W = sum of 4 outer products
        float W[4][4];
#pragma unroll
        for (int s = 0; s < 4; ++s) {
            bool sc = (cx[s].base != cbmin);
            float C0 = sc ? 0.f : cx[s].w0;
            float C1 = sc ? cx[s].w0 : cx[s].w1;
            float C2 = sc ? cx[s].w1 : cx[s].w2;
            float C3 = sc ? cx[s].w2 : 0.f;
            bool sr = (ry[s].base != rbmin);
            float R0 = sr ? 0.f : ry[s].w0;
            float R1 = sr ? ry[s].w0 : ry[s].w1;
            float R2 = sr ? ry[s].w1 : ry[s].w2;
            float R3 = sr ? ry[s].w2 : 0.f;
            float C[4] = {C0, C1, C2, C3};
            float R[4] = {R0, R1, R2, R3};
            if (s == 0) {
#pragma unroll
                for (int r = 0; r < 4; ++r)
#pragma unroll
                    for (int c = 0; c < 4; ++c)
                        W[r][c] = R[r] * C[c];
            } else {
#pragma unroll
                for (int r = 0; r < 4; ++r)
#pragma unroll
                    for (int c = 0; c < 4; ++c)
                        W[r][c] = fmaf(R[r], C[c], W[r][c]);
            }
        }

        // right-edge safety: weights for columns > 255 are exactly zero, so
        // rotating right against base 252 is exact. shift <= 3.
        int base = cbmin;
        if (cbmin > 252) {
            int shift = cbmin - 252;
            base = 252;
            for (int s = 0; s < shift; ++s) {
#pragma unroll
                for (int r = 0; r < 4; ++r) {
                    W[r][3] = W[r][2]; W[r][2] = W[r][1];
                    W[r][1] = W[r][0]; W[r][0] = 0.f;
                }
            }
        }

        int e0 = rbmin * 256 + base;
        int e1 = min(rbmin + 1, 255) * 256 + base;  // rows past 255 carry zero
        int e2 = min(rbmin + 2, 255) * 256 + base;  //   weight; aliasing row
        int e3 = min(rbmin + 3, 255) * 256 + base;  //   255 is harmless

        // ---- MLP: issue ALL 12 loads before any FMA (one latency exposure).
        const float* p0 = xb;
        const float* p1 = xb + 65536;
        const float* p2 = xb + 131072;
        floatx4 A0 = load4(p0 + e0);
        floatx4 A1 = load4(p0 + e1);
        floatx4 A2 = load4(p0 + e2);
        floatx4 A3 = load4(p0 + e3);
        floatx4 B0 = load4(p1 + e0);
        floatx4 B1 = load4(p1 + e1);
        floatx4 B2 = load4(p1 + e2);
        floatx4 B3 = load4(p1 + e3);
        floatx4 D0 = load4(p2 + e0);
        floatx4 D1 = load4(p2 + e1);
        floatx4 D2 = load4(p2 + e2);
        floatx4 D3 = load4(p2 + e3);

        {
            float s0 = fmaf(W[0][3], A0.w, fmaf(W[0][2], A0.z, fmaf(W[0][1], A0.y, W[0][0] * A0.x)));
            float s1 = fmaf(W[1][3], A1.w, fmaf(W[1][2], A1.z, fmaf(W[1][1], A1.y, W[1][0] * A1.x)));
            float s2 = fmaf(W[2][3], A2.w, fmaf(W[2][2], A2.z, fmaf(W[2][1], A2.y, W[2][0] * A2.x)));
            float s3 = fmaf(W[3][3], A3.w, fmaf(W[3][2], A3.z, fmaf(W[3][1], A3.y, W[3][0] * A3.x)));
            acc[0] = (s0 + s1) + (s2 + s3);
        }
        {
            float s0 = fmaf(W[0][3], B0.w, fmaf(W[0][2], B0.z, fmaf(W[0][1], B0.y, W[0][0] * B0.x)));
            float s1 = fmaf(W[1][3], B1.w, fmaf(W[1][2], B1.z, fmaf(W[1][1], B1.y, W[1][0] * B1.x)));
            float s2 = fmaf(W[2][3], B2.w, fmaf(W[2][2], B2.z, fmaf(W[2][1], B2.y, W[2][0] * B2.x)));
            float s3 = fmaf(W[3][3], B3.w, fmaf(W[3][2], B3.z, fmaf(W[3][1], B3.y, W[3][0] * B3.x)));
            acc[1] = (s0 + s1) + (s2 + s3);
        }
        {
            float s0 = fmaf(W[0][3], D0.w, fmaf(W[0][2], D0.z, fmaf(W[0][1], D0.y, W[0][0] * D0.x)));
            float s1 = fmaf(W[1][3], D1.w, fmaf(W[1][2], D1.z, fmaf(W[1][1], D1.y, W[1][0] * D1.x)));
            float s2 = fmaf(W[2][3], D2.w, fmaf(W[2][2], D2.z, fmaf(W[2][1], D2.y, W[2][0] * D2.x)));
            float s3 = fmaf(W[3][3], D3.w, fmaf(W[3][2], D3.z, fmaf(W[3][1], D3.y, W[3][0] * D3.x)));
            acc[2] = (s0 + s1) + (s2 + s3);
        }
    } else {
        pair_accum(cx[0], cx[1], ry[0], ry[1], xb, acc);
        pair_accum(cx[2], cx[3], ry[2], ry[3], xb, acc);
    }

    int obase = ((b * 3) * 256 + i) * 256 + j;
    out[obase]          = 0.25f * acc[0];
    out[obase + 65536]  = 0.25f * acc[1];
    out[obase + 131072] = 0.25f * acc[2];
}

extern "C" void kernel_launch(void* const* d_in, const int* in_sizes, int n_in,
                              void* d_out, int out_size, void* d_ws, size_t ws_size,
                              hipStream_t stream) {
    const float* x      = (const float*)d_in[0];
    const float* paramP = (const float*)d_in[1];
    const float* paramM = (const float*)d_in[2];
    const float* gumbel = (const float*)d_in[3];
    const float* eps    = (const float*)d_in[4];
    const int*   idx    = (const int*)d_in[5];
    float* out = (float*)d_out;
    int N = in_sizes[1] / 7;

    // 1) streaming prefetch of x into L3 (12.6MB, ~2-3us)
    int n4 = (16 * 3 * 65536) / 4;   // 786432 float4s
    hipLaunchKernelGGL(prefetch_x, dim3(1024, 1, 1), dim3(256, 1, 1), 0, stream,
                       x, n4);

    // 2) gather kernel (unchanged math)
    hipLaunchKernelGGL(fused_warp, dim3(4, 64, 16), dim3(64, 4, 1), 0, stream,
                       x, paramP, paramM, gumbel, eps, idx, out, N);
}

// Round 10
// 90.214 us; speedup vs baseline: 1.0530x; 1.0308x over previous
//
#include <hip/hip_runtime.h>
#include <math.h>

// Exact fusion of: resize(256->1024) -> warp_perspective(affine) -> resize(1024->256).
// R10 (final): revert R7/R9's prefetch (regressed +3.7us: extra dispatch cost
// with no fetch-time saving -> L3-cold-fetch theory falsified). This is the
// best measured configuration: single launch, 64x1 wave tiling, per-wave
// redundant matrix (no barrier/LDS), all 12 window loads hoisted (one latency
// exposure), contiguous per-wave stores. 89.3-89.8us measured (R0/R4/R5 tied).
//
// Session ledger (kernel portion ~29us, invariant):
//   R1 LDS staging        -10us (ds_read issue cost + occupancy drop)
//   R2 XCD swizzle          0   (per-image working set already L2-resident)
//   R3 wave-uniform sweep -17us (4x VALU, serialized loads)
//   R4 MLP hoist/no-bar     0   (compiler already batches; kept - harmless)
//   R5 64x1 tiling          0   (footprint/instr not the limiter; kept)
//   R6 4-out vertical dedup -6us (chain check + 4x fewer waves)
//   R9 L3 prefetch          -4us (extra dispatch; fetch wasn't the bound)
// Structural ceiling: timed region = harness fill ~43us (256MB @ 80% HBM
// peak, at ceiling) + ~17us fixed dispatch overhead + ~29us gather kernel
// whose data-dependent line set and dependent chains are invariant to all
// source-level restructuring attempted.

typedef float floatx4 __attribute__((ext_vector_type(4)));

__device__ __forceinline__ floatx4 load4(const float* p) {
    floatx4 v;
    __builtin_memcpy(&v, p, sizeof(v));  // 4B-aligned 16B load -> dwordx4
    return v;
}

struct Up { int i0; float w; };

__device__ __forceinline__ Up upc(int v) {
    float u = fmaf(0.25f, (float)v, -0.375f);
    u = fminf(fmaxf(u, 0.0f), 255.0f);
    float f = floorf(u);
    Up r; r.i0 = (int)f; r.w = u - f;
    return r;
}

struct Trip { float w0, w1, w2; int base; };

__device__ __forceinline__ Trip merged3(float s) {
    float f = floorf(s);
    float fr = s - f;
    int v0 = (int)f;
    int v1 = min(v0 + 1, 1023);
    Up c0 = upc(v0), c1 = upc(v1);
    float A0 = 1.0f - fr, A1 = fr;
    float b0 = A1 * (1.0f - c1.w), b1 = A1 * c1.w;
    bool d = (c1.i0 != c0.i0);
    Trip t;
    t.w0 = A0 * (1.0f - c0.w) + (d ? 0.0f : b0);
    t.w1 = A0 * c0.w + (d ? b0 : b1);
    t.w2 = d ? b1 : 0.0f;
    t.base = c0.i0;
    return t;
}

// Exact round-4 pair accumulation (fallback for rare wide-spread threads).
__device__ __forceinline__ void pair_accum(
    Trip cA, Trip cB, Trip rA, Trip rB,
    const float* __restrict__ xb, float* acc)
{
    int cb = min(cA.base, cB.base);
    int rb = min(rA.base, rB.base);
    float CA[4], CB[4], RA[4], RB[4];
    bool sa_ = (cA.base != cb);
    CA[0] = sa_ ? 0.f : cA.w0;  CA[1] = sa_ ? cA.w0 : cA.w1;
    CA[2] = sa_ ? cA.w1 : cA.w2;  CA[3] = sa_ ? cA.w2 : 0.f;
    bool sb_ = (cB.base != cb);
    CB[0] = sb_ ? 0.f : cB.w0;  CB[1] = sb_ ? cB.w0 : cB.w1;
    CB[2] = sb_ ? cB.w1 : cB.w2;  CB[3] = sb_ ? cB.w2 : 0.f;
    bool ra_ = (rA.base != rb);
    RA[0] = ra_ ? 0.f : rA.w0;  RA[1] = ra_ ? rA.w0 : rA.w1;
    RA[2] = ra_ ? rA.w1 : rA.w2;  RA[3] = ra_ ? rA.w2 : 0.f;
    bool rb_ = (rB.base != rb);
    RB[0] = rb_ ? 0.f : rB.w0;  RB[1] = rb_ ? rB.w0 : rB.w1;
    RB[2] = rb_ ? rB.w1 : rB.w2;  RB[3] = rb_ ? rB.w2 : 0.f;

    float W[4][4];
#pragma unroll
    for (int r = 0; r < 4; ++r)
#pragma unroll
        for (int c = 0; c < 4; ++c)
            W[r][c] = fmaf(RB[r], CB[c], RA[r] * CA[c]);

    int base = cb;
    if (cb > 252) {
        int shift = cb - 252;
        base = 252;
        for (int s = 0; s < shift; ++s) {
#pragma unroll
            for (int r = 0; r < 4; ++r) {
                W[r][3] = W[r][2]; W[r][2] = W[r][1];
                W[r][1] = W[r][0]; W[r][0] = 0.f;
            }
        }
    }
    int e0 = rb * 256 + base;
    int e1 = min(rb + 1, 255) * 256 + base;
    int e2 = min(rb + 2, 255) * 256 + base;
    int e3 = min(rb + 3, 255) * 256 + base;
#pragma unroll
    for (int ch = 0; ch < 3; ++ch) {
        const float* pc = xb + ch * 65536;
        floatx4 L0 = load4(pc + e0);
        floatx4 L1 = load4(pc + e1);
        floatx4 L2 = load4(pc + e2);
        floatx4 L3 = load4(pc + e3);
        float s0 = fmaf(W[0][3], L0.w, fmaf(W[0][2], L0.z, fmaf(W[0][1], L0.y, W[0][0] * L0.x)));
        float s1 = fmaf(W[1][3], L1.w, fmaf(W[1][2], L1.z, fmaf(W[1][1], L1.y, W[1][0] * L1.x)));
        float s2 = fmaf(W[2][3], L2.w, fmaf(W[2][2], L2.z, fmaf(W[2][1], L2.y, W[2][0] * L2.x)));
        float s3 = fmaf(W[3][3], L3.w, fmaf(W[3][2], L3.z, fmaf(W[3][1], L3.y, W[3][0] * L3.x)));
        acc[ch] += (s0 + s1) + (s2 + s3);
    }
}

__global__ __launch_bounds__(256) void fused_warp(
    const float* __restrict__ x,
    const float* __restrict__ paramP, const float* __restrict__ paramM,
    const float* __restrict__ gumbel_u, const float* __restrict__ eps,
    const int* __restrict__ idx,
    float* __restrict__ out, int N)
{
    int b = blockIdx.z;
    int lane = threadIdx.x;      // 0..63: output column within the 64-wide tile
    int wid  = threadIdx.y;      // 0..3 : output row within the 4-tall tile

    // ---- per-wave redundant matrix computation (no barrier, no LDS) ----
    float dec = 0.f, sMv = 0.f;
    if (lane < 7) {
        int k = lane;
        int id = idx[b];
        float vP = paramP[k * N + id];
        float pP = 1.0f / (1.0f + expf(-vP));
        float l0 = logf(pP);
        float l1 = logf(1.0f - pP);
        float u0 = gumbel_u[(k * 16 + b) * 2 + 0];
        float u1 = gumbel_u[(k * 16 + b) * 2 + 1];
        float g0 = -logf(-logf(u0));
        float g1 = -logf(-logf(u1));
        dec = (l0 + g0 >= l1 + g1) ? 1.0f : 0.0f;  // argmax tie -> index 0
        float vM = paramM[k * N + id];
        float sig = 1.0f / (1.0f + expf(-vM));
        sMv = sig * eps[k * 16 + b];
    }
    float sP[7], sM[7];
#pragma unroll
    for (int k = 0; k < 7; ++k) {
        sP[k] = __shfl(dec, k, 64);
        sM[k] = __shfl(sMv, k, 64);
    }

    float ang = sP[0] * sM[0] * 30.0f;
    float rad = ang * 0.017453292519943295f;
    float ca = cosf(rad), sa = sinf(rad);
    float sx = 1.0f + sP[5] * sM[5] * 0.5f;
    float sy = 1.0f + sP[6] * sM[6] * 0.5f;
    float sr00 = ca * sx, sr01 = sa * sy;
    float sr10 = -sa * sx, sr11 = ca * sy;
    float t0 = 128.0f - (sr00 + sr01) * 128.0f;
    float t1 = 128.0f - (sr10 + sr11) * 128.0f;
    float tx2 = 256.0f * sP[1] * sM[1] * 0.45f;
    float ty2 = 256.0f * sP[2] * sM[2] * 0.45f;
    float sh01 = sP[3] * sM[3] * 0.3f;
    float sh10 = sP[4] * sM[4] * 0.3f;
    float e0m = t0 + tx2, e1m = t1 + ty2;
    float a  = sr00 + sh01 * sr10;
    float bb = sr01 + sh01 * sr11;
    float txm = e0m + sh01 * e1m;
    float c  = sh10 * sr00 + sr10;
    float d  = sh10 * sr01 + sr11;
    float tym = sh10 * e0m + e1m;
    float det = a * d - bb * c;
    float rdet = 1.0f / det;
    float m00 = d * rdet;
    float m01 = -bb * rdet;
    float m02 = (bb * tym - d * txm) * rdet;
    float m10 = -c * rdet;
    float m11 = a * rdet;
    float m12 = (c * txm - a * tym) * rdet;

    // ---- 64x1 wave tiling: all 64 lanes on ONE output row; contiguous stores.
    int j = blockIdx.x * 64 + lane;
    int i = blockIdx.y * 4 + wid;

    const float* xb = x + b * 3 * 65536;

    float XA = (float)(4 * j + 1);
    float Y0 = (float)(4 * i + 1);
    float x0 = fmaf(m00, XA, fmaf(m01, Y0, m02));
    float y0 = fmaf(m10, XA, fmaf(m11, Y0, m12));
    float xs[4], ys[4];
    xs[0] = x0;        ys[0] = y0;
    xs[1] = x0 + m00;  ys[1] = y0 + m10;
    xs[2] = x0 + m01;  ys[2] = y0 + m11;
    xs[3] = xs[1] + m01; ys[3] = ys[1] + m11;

    Trip cx[4], ry[4];
#pragma unroll
    for (int s = 0; s < 4; ++s) {
        cx[s] = merged3(fminf(fmaxf(xs[s], 0.f), 1023.f));
        ry[s] = merged3(fminf(fmaxf(ys[s], 0.f), 1023.f));
    }

    int cbmin = min(min(cx[0].base, cx[1].base), min(cx[2].base, cx[3].base));
    int cbmax = max(max(cx[0].base, cx[1].base), max(cx[2].base, cx[3].base));
    int rbmin = min(min(ry[0].base, ry[1].base), min(ry[2].base, ry[3].base));
    int rbmax = max(max(ry[0].base, ry[1].base), max(ry[2].base, ry[3].base));

    float acc[3] = {0.f, 0.f, 0.f};

    if (((cbmax - cbmin) | (rbmax - rbmin)) <= 1) {
        // ---- fast path: single 4x4 union window, W = sum of 4 outer products
        float W[4][4];
#pragma unroll
        for (int s = 0; s < 4; ++s) {
            bool sc = (cx[s].base != cbmin);
            float C0 = sc ? 0.f : cx[s].w0;
            float C1 = sc ? cx[s].w0 : cx[s].w1;
            float C2 = sc ? cx[s].w1 : cx[s].w2;
            float C3 = sc ? cx[s].w2 : 0.f;
            bool sr = (ry[s].base != rbmin);
            float R0 = sr ? 0.f : ry[s].w0;
            float R1 = sr ? ry[s].w0 : ry[s].w1;
            float R2 = sr ? ry[s].w1 : ry[s].w2;
            float R3 = sr ? ry[s].w2 : 0.f;
            float C[4] = {C0, C1, C2, C3};
            float R[4] = {R0, R1, R2, R3};
            if (s == 0) {
#pragma unroll
                for (int r = 0; r < 4; ++r)
#pragma unroll
                    for (int c = 0; c < 4; ++c)
                        W[r][c] = R[r] * C[c];
            } else {
#pragma unroll
                for (int r = 0; r < 4; ++r)
#pragma unroll
                    for (int c = 0; c < 4; ++c)
                        W[r][c] = fmaf(R[r], C[c], W[r][c]);
            }
        }

        // right-edge safety: weights for columns > 255 are exactly zero, so
        // rotating right against base 252 is exact. shift <= 3.
        int base = cbmin;
        if (cbmin > 252) {
            int shift = cbmin - 252;
            base = 252;
            for (int s = 0; s < shift; ++s) {
#pragma unroll
                for (int r = 0; r < 4; ++r) {
                    W[r][3] = W[r][2]; W[r][2] = W[r][1];
                    W[r][1] = W[r][0]; W[r][0] = 0.f;
                }
            }
        }

        int e0 = rbmin * 256 + base;
        int e1 = min(rbmin + 1, 255) * 256 + base;  // rows past 255 carry zero
        int e2 = min(rbmin + 2, 255) * 256 + base;  //   weight; aliasing row
        int e3 = min(rbmin + 3, 255) * 256 + base;  //   255 is harmless

        // ---- MLP: issue ALL 12 loads before any FMA (one latency exposure).
        const float* p0 = xb;
        const float* p1 = xb + 65536;
        const float* p2 = xb + 131072;
        floatx4 A0 = load4(p0 + e0);
        floatx4 A1 = load4(p0 + e1);
        floatx4 A2 = load4(p0 + e2);
        floatx4 A3 = load4(p0 + e3);
        floatx4 B0 = load4(p1 + e0);
        floatx4 B1 = load4(p1 + e1);
        floatx4 B2 = load4(p1 + e2);
        floatx4 B3 = load4(p1 + e3);
        floatx4 D0 = load4(p2 + e0);
        floatx4 D1 = load4(p2 + e1);
        floatx4 D2 = load4(p2 + e2);
        floatx4 D3 = load4(p2 + e3);

        {
            float s0 = fmaf(W[0][3], A0.w, fmaf(W[0][2], A0.z, fmaf(W[0][1], A0.y, W[0][0] * A0.x)));
            float s1 = fmaf(W[1][3], A1.w, fmaf(W[1][2], A1.z, fmaf(W[1][1], A1.y, W[1][0] * A1.x)));
            float s2 = fmaf(W[2][3], A2.w, fmaf(W[2][2], A2.z, fmaf(W[2][1], A2.y, W[2][0] * A2.x)));
            float s3 = fmaf(W[3][3], A3.w, fmaf(W[3][2], A3.z, fmaf(W[3][1], A3.y, W[3][0] * A3.x)));
            acc[0] = (s0 + s1) + (s2 + s3);
        }
        {
            float s0 = fmaf(W[0][3], B0.w, fmaf(W[0][2], B0.z, fmaf(W[0][1], B0.y, W[0][0] * B0.x)));
            float s1 = fmaf(W[1][3], B1.w, fmaf(W[1][2], B1.z, fmaf(W[1][1], B1.y, W[1][0] * B1.x)));
            float s2 = fmaf(W[2][3], B2.w, fmaf(W[2][2], B2.z, fmaf(W[2][1], B2.y, W[2][0] * B2.x)));
            float s3 = fmaf(W[3][3], B3.w, fmaf(W[3][2], B3.z, fmaf(W[3][1], B3.y, W[3][0] * B3.x)));
            acc[1] = (s0 + s1) + (s2 + s3);
        }
        {
            float s0 = fmaf(W[0][3], D0.w, fmaf(W[0][2], D0.z, fmaf(W[0][1], D0.y, W[0][0] * D0.x)));
            float s1 = fmaf(W[1][3], D1.w, fmaf(W[1][2], D1.z, fmaf(W[1][1], D1.y, W[1][0] * D1.x)));
            float s2 = fmaf(W[2][3], D2.w, fmaf(W[2][2], D2.z, fmaf(W[2][1], D2.y, W[2][0] * D2.x)));
            float s3 = fmaf(W[3][3], D3.w, fmaf(W[3][2], D3.z, fmaf(W[3][1], D3.y, W[3][0] * D3.x)));
            acc[2] = (s0 + s1) + (s2 + s3);
        }
    } else {
        pair_accum(cx[0], cx[1], ry[0], ry[1], xb, acc);
        pair_accum(cx[2], cx[3], ry[2], ry[3], xb, acc);
    }

    int obase = ((b * 3) * 256 + i) * 256 + j;
    out[obase]          = 0.25f * acc[0];
    out[obase + 65536]  = 0.25f * acc[1];
    out[obase + 131072] = 0.25f * acc[2];
}

extern "C" void kernel_launch(void* const* d_in, const int* in_sizes, int n_in,
                              void* d_out, int out_size, void* d_ws, size_t ws_size,
                              hipStream_t stream) {
    const float* x      = (const float*)d_in[0];
    const float* paramP = (const float*)d_in[1];
    const float* paramM = (const float*)d_in[2];
    const float* gumbel = (const float*)d_in[3];
    const float* eps    = (const float*)d_in[4];
    const int*   idx    = (const int*)d_in[5];
    float* out = (float*)d_out;
    int N = in_sizes[1] / 7;

    hipLaunchKernelGGL(fused_warp, dim3(4, 64, 16), dim3(64, 4, 1), 0, stream,
                       x, paramP, paramM, gumbel, eps, idx, out, N);
}